// Round 12
// baseline (1379.151 us; speedup 1.0000x reference)
//
#include <hip/hip_runtime.h>

typedef __attribute__((ext_vector_type(8))) short bf16x8;
typedef __attribute__((ext_vector_type(4))) float f32x4;

#define D_DIM 256
#define K_CODES 8192
#define N_TOK 16384
#define LCAP 28
#define CAP_G 112
#define MQ 2400u          // capture/filter window in q19 counts (1.8e-4) > 2*eps_worst(bf16)
#define QSCALE19 13107200.0f
#define QOFF 0.02f

// ---------- numpy-exact helpers (pairwise sum of squares, n=256) ----------
__device__ __forceinline__ float pw128_sq(const float* a, int stride) {
    float r[8];
    #pragma unroll
    for (int j = 0; j < 8; ++j) { float v = a[j * stride]; r[j] = __fmul_rn(v, v); }
    for (int i = 8; i < 128; i += 8) {
        #pragma unroll
        for (int j = 0; j < 8; ++j) { float v = a[(i + j) * stride]; r[j] = __fadd_rn(r[j], __fmul_rn(v, v)); }
    }
    return __fadd_rn(__fadd_rn(__fadd_rn(r[0], r[1]), __fadd_rn(r[2], r[3])),
                     __fadd_rn(__fadd_rn(r[4], r[5]), __fadd_rn(r[6], r[7])));
}
__device__ __forceinline__ float sumsq256(const float* a, int stride) {
    return __fadd_rn(pw128_sq(a, stride), pw128_sq(a + 128 * stride, stride));
}

__device__ __forceinline__ unsigned f2bf_u(float f) {   // RNE float->bf16 bits
    unsigned u = __float_as_uint(f);
    return (u + 0x7FFFu + ((u >> 16) & 1u)) >> 16;
}

__device__ __forceinline__ unsigned q19(float s) {      // monotone 19-bit score quantizer
    int q = (int)((s + QOFF) * QSCALE19);
    q = q < 0 ? 0 : (q > 524287 ? 524287 : q);
    return (unsigned)q;
}

// ---------- fused prep: ecvt (2048 blocks) + enorm16 (512) + znorm/zeroing (64) ----------
__global__ __launch_bounds__(256) void prep_kernel(const float* __restrict__ z_e,
                                                   const float* __restrict__ embed,
                                                   float* __restrict__ e_norm,
                                                   float* __restrict__ z_norm,
                                                   ushort* __restrict__ e_bf,
                                                   unsigned* __restrict__ ccount,
                                                   int* __restrict__ counts) {
    int bid = blockIdx.x;
    if (bid < 2048) {                      // ecvt: fp32 -> bf16 codebook
        int i = bid * 256 + threadIdx.x;   // 524288 float4s
        float4 v = reinterpret_cast<const float4*>(embed)[i];
        ushort4 o;
        o.x = (ushort)f2bf_u(v.x); o.y = (ushort)f2bf_u(v.y);
        o.z = (ushort)f2bf_u(v.z); o.w = (ushort)f2bf_u(v.w);
        reinterpret_cast<ushort4*>(e_bf)[i] = o;
    } else if (bid < 2560) {               // enorm: 16 lanes per code, numpy-pairwise-exact
        int tid = threadIdx.x;
        int code = (bid - 2048) * 16 + (tid >> 4);
        int sub = tid & 15;                // half = sub>>3, j = sub&7
        const float* base = embed + code * 256 + (sub >> 3) * 128 + (sub & 7);
        float v = base[0];
        float r = __fmul_rn(v, v);         // r[j] chain, i = 8..120 step 8
        #pragma unroll
        for (int i = 8; i < 128; i += 8) { v = base[i]; r = __fadd_rn(r, __fmul_rn(v, v)); }
        r = __fadd_rn(r, __shfl_xor(r, 1, 64));   // (r0+r1), (r2+r3), ...
        r = __fadd_rn(r, __shfl_xor(r, 2, 64));   // (r01+r23), (r45+r67)
        r = __fadd_rn(r, __shfl_xor(r, 4, 64));   // pw128
        r = __fadd_rn(r, __shfl_xor(r, 8, 64));   // pw128_lo + pw128_hi
        if (sub == 0) e_norm[code] = r;
    } else {                               // znorm + zero ccount/counts/loss_sum
        int n = (bid - 2560) * 256 + threadIdx.x;   // 16384
        int b = n >> 10, hw = n & 1023;
        z_norm[n] = sumsq256(z_e + b * 262144 + hw, 1024);
        ccount[n] = 0;
        if (n < 8193) counts[n] = 0;       // counts[8192] == adjacent loss_sum
    }
}

// ---------- MFMA approx scores: 8 waves/block (32 waves/CU), shared-qmin capture ----------
// grid 1024 = 256 token-panels x 4 slabs; slab constant per XCD; 4 blocks/CU.
// candidate word: (q19:19 | code:13). Capture -> LDS; one flush at end.
// 4 blocks x LCAP(28) = 112 = CAP_G: global cand can never truncate.
__global__ __launch_bounds__(512, 8) void mfma_argmin_kernel(
    const float* __restrict__ z_e, const ushort* __restrict__ e_bf,
    const float* __restrict__ e_norm,
    unsigned* __restrict__ ccount, unsigned* __restrict__ cand)
{
    __shared__ char zs[32768];    // 64 token-rows x 512B bf16, byte ^= ((row&7)<<4)
    __shared__ unsigned cand_l[64][LCAP];
    __shared__ unsigned cnt_l[64];
    __shared__ unsigned qmin_l[64];   // block-shared running min (q19), monotone decreasing

    const int tid = threadIdx.x;
    const int l   = tid & 63;
    const int wv  = tid >> 6;                    // 0..7
    const int col = l & 15;
    const int kg  = l >> 4;
    const int bid = (int)blockIdx.x;
    const int slab= (bid >> 1) & 3;              // == (XCD id)>>1: slab L2-resident per XCD
    const int mb  = ((bid >> 3) << 1) | (bid & 1);  // 0..255
    const int n0  = mb * 64;
    const int bb  = n0 >> 10;
    const int hw0 = n0 & 1023;
    const int cs  = slab * 2048 + wv * 256;      // this wave's 256-code range

    if (tid < 64) {
        cnt_l[tid] = 0;
        cand_l[tid][LCAP - 1] = 0xFFFFFFFFu;     // overflow atomicMin slot
        qmin_l[tid] = 0x0FFFFFFFu;               // large, no wrap with +MQ
    }

    // stage z panel: fp32 -> bf16, transpose [d][hw] -> [token][d], swizzled (round-3 proven)
    {
        const float* zb = z_e + bb * 262144 + hw0 + l;
        int swz = (l & 7) << 4;
        #pragma unroll 4
        for (int it = 0; it < 16; ++it) {
            int d = it * 16 + wv * 2;            // 8 waves cover all even-d pairs
            float a0 = zb[d * 1024];
            float a1 = zb[d * 1024 + 1024];
            unsigned pk = f2bf_u(a0) | (f2bf_u(a1) << 16);
            *(unsigned*)(zs + l * 512 + ((d * 2) ^ swz)) = pk;
        }
    }
    __syncthreads();

    const int a_swz = (col & 7) << 4;
    const char* bbase = (const char*)e_bf + (size_t)(cs + col) * 512 + kg * 16;
    const float* enb = e_norm + cs + col;

    f32x4 acc[4][4];
    bf16x8 bA[4], bB[4];

    // step = t*8 + kb; t in [0,4) tiles of 64 codes, kb in [0,8) K-chunks of 32
    #define LDB(dst, step) { int _t = (step) >> 3, _kb = (step) & 7;                         \
        _Pragma("unroll")                                                                    \
        for (int nt = 0; nt < 4; ++nt)                                                       \
            dst[nt] = *(const bf16x8*)(bbase + _t * 32768 + nt * 8192 + _kb * 64); }

    #define COMPUTE(bf, step) {                                                              \
        int _kb = (step) & 7;                                                                \
        if (_kb == 0) {                                                                      \
            _Pragma("unroll")                                                                \
            for (int rt = 0; rt < 4; ++rt)                                                   \
                _Pragma("unroll")                                                            \
                for (int nt = 0; nt < 4; ++nt) acc[rt][nt] = f32x4{0.f, 0.f, 0.f, 0.f};      \
        }                                                                                    \
        int a_off = (_kb * 64 + kg * 16) ^ a_swz;                                            \
        _Pragma("unroll")                                                                    \
        for (int rt = 0; rt < 4; ++rt) {                                                     \
            bf16x8 afr = *(const bf16x8*)(zs + (rt * 16 + col) * 512 + a_off);               \
            _Pragma("unroll")                                                                \
            for (int nt = 0; nt < 4; ++nt)                                                   \
                acc[rt][nt] = __builtin_amdgcn_mfma_f32_16x16x32_bf16(afr, bf[nt], acc[rt][nt], 0, 0, 0); \
        }                                                                                    \
        if (_kb == 7) {                                                                      \
            int _t = (step) >> 3;                                                            \
            int cb = cs + _t * 64;                                                           \
            float en[4];                                                                     \
            _Pragma("unroll")                                                                \
            for (int nt = 0; nt < 4; ++nt) en[nt] = enb[_t * 64 + nt * 16];                  \
            _Pragma("unroll")                                                                \
            for (int rt = 0; rt < 4; ++rt)                                                   \
                _Pragma("unroll")                                                            \
                for (int nt = 0; nt < 4; ++nt)                                               \
                    _Pragma("unroll")                                                        \
                    for (int r = 0; r < 4; ++r)                                              \
                        acc[rt][nt][r] = fmaf(-2.0f, acc[rt][nt][r], en[nt]);                \
            _Pragma("unroll")                                                                \
            for (int rt = 0; rt < 4; ++rt) {                                                 \
                _Pragma("unroll")                                                            \
                for (int r = 0; r < 4; ++r) {                                                \
                    float m4 = fminf(fminf(acc[rt][0][r], acc[rt][1][r]),                    \
                                     fminf(acc[rt][2][r], acc[rt][3][r]));                   \
                    float tm = m4;                                                           \
                    tm = fminf(tm, __shfl_xor(tm, 1, 64));                                   \
                    tm = fminf(tm, __shfl_xor(tm, 2, 64));                                   \
                    tm = fminf(tm, __shfl_xor(tm, 4, 64));                                   \
                    tm = fminf(tm, __shfl_xor(tm, 8, 64));                                   \
                    int tl = rt * 16 + kg * 4 + r;       /* block-local token */             \
                    unsigned qtm = q19(tm);                                                  \
                    unsigned cur = qmin_l[tl];           /* stale-read safe (monotone) */    \
                    unsigned thr = (cur < qtm ? cur : qtm) + MQ;                             \
                    if (q19(m4) < thr) {                                                     \
                        _Pragma("unroll")                                                    \
                        for (int nt2 = 0; nt2 < 4; ++nt2) {                                  \
                            unsigned qs = q19(acc[rt][nt2][r]);                              \
                            if (qs < thr) {                                                  \
                                unsigned w = (qs << 13)                                      \
                                           | (unsigned)(cb + nt2 * 16 + col);                \
                                unsigned p = atomicAdd(&cnt_l[tl], 1u);     /* LDS atomic */ \
                                if (p < LCAP - 1) cand_l[tl][p] = w;                         \
                                else atomicMin(&cand_l[tl][LCAP - 1], w);                    \
                            }                                                                \
                        }                                                                    \
                        if (qtm < cur) atomicMin(&qmin_l[tl], qtm);                          \
                    }                                                                        \
                }                                                                            \
            }                                                                                \
        }                                                                                    \
    }

    LDB(bA, 0);
    for (int sp = 0; sp < 16; ++sp) {       // 2 steps per iteration; buffers statically named
        int step = sp * 2;
        LDB(bB, step + 1);
        COMPUTE(bA, step);
        if (step + 2 < 32) LDB(bA, step + 2);
        COMPUTE(bB, step + 1);
    }
    #undef LDB
    #undef COMPUTE

    // flush block-local candidates: one global atomic per token per block
    __syncthreads();
    if (tid < 64) {
        unsigned cl = cnt_l[tid]; if (cl > LCAP) cl = LCAP;
        if (cl) {
            int token = n0 + tid;
            unsigned p = atomicAdd(&ccount[token], cl);
            for (unsigned i = 0; i < cl && p + i < CAP_G; ++i)
                cand[token * CAP_G + p + i] = cand_l[tid][i];
        }
    }
}

// ---------- filter by quantized approx score, exact fp32 rescore of survivors ----------
__global__ __launch_bounds__(256) void rescore_kernel(
    const float* __restrict__ z_e, const float* __restrict__ embed,
    const float* __restrict__ e_norm, const float* __restrict__ z_norm,
    const unsigned* __restrict__ ccount, const unsigned* __restrict__ cand,
    int* __restrict__ codes, float* __restrict__ out, int* __restrict__ counts)
{
    __shared__ float zrow[4][256];
    int wv = threadIdx.x >> 6, l = threadIdx.x & 63;
    int n = blockIdx.x * 4 + wv;
    // coalesced stage: thread d loads float4 = 4 consecutive tokens at depth d
    {
        int n0 = blockIdx.x * 4;
        int b = n0 >> 10, hw0 = n0 & 1023;
        float4 v = *reinterpret_cast<const float4*>(z_e + b * 262144 + threadIdx.x * 1024 + hw0);
        zrow[0][threadIdx.x] = v.x; zrow[1][threadIdx.x] = v.y;
        zrow[2][threadIdx.x] = v.z; zrow[3][threadIdx.x] = v.w;
    }
    __syncthreads();

    unsigned cnt = ccount[n]; if (cnt > CAP_G) cnt = CAP_G;
    unsigned c0 = ((unsigned)l      < cnt) ? cand[n * CAP_G + l]      : 0xFFFFFFFFu;
    unsigned c1 = ((unsigned)l + 64 < cnt) ? cand[n * CAP_G + l + 64] : 0xFFFFFFFFu;
    unsigned qm = min(c0 >> 13, c1 >> 13);
    #pragma unroll
    for (int m = 1; m < 64; m <<= 1) qm = min(qm, (unsigned)__shfl_xor((int)qm, m, 64));
    unsigned qthr = qm + MQ;

    float best = 3.4e38f; int bidx = 0x7FFFFFFF;
    float zn = z_norm[n];
    #pragma unroll
    for (int pass = 0; pass < 2; ++pass) {
        unsigned cd = pass ? c1 : c0;
        if ((cd >> 13) <= qthr) {          // ~1-2 survivors per token
            int idx = (int)(cd & 8191u);
            const float* er = embed + idx * D_DIM;
            float dot = 0.f;
            for (int d = 0; d < 256; d += 4) {  // ascending-d fmaf chain (bit-identical to round-2)
                float4 e4 = *reinterpret_cast<const float4*>(er + d);
                dot = fmaf(zrow[wv][d],     e4.x, dot);
                dot = fmaf(zrow[wv][d + 1], e4.y, dot);
                dot = fmaf(zrow[wv][d + 2], e4.z, dot);
                dot = fmaf(zrow[wv][d + 3], e4.w, dot);
            }
            float s = __fsub_rn(__fadd_rn(zn, e_norm[idx]), __fmul_rn(2.0f, dot));
            if (s < best || (s == best && idx < bidx)) { best = s; bidx = idx; }
        }
    }
    #pragma unroll
    for (int m = 1; m < 64; m <<= 1) {      // min with lowest-index tie-break
        float s2 = __shfl_xor(best, m, 64);
        int   i2 = __shfl_xor(bidx, m, 64);
        if (s2 < best || (s2 == best && i2 < bidx)) { best = s2; bidx = i2; }
    }
    if (l == 0) {
        codes[n] = bidx;
        out[8388608 + n] = (float)bidx;
        atomicAdd(&counts[bidx], 1);
    }
}

// ---------- outputs: LDS-staged gather (coalesced embed reads) + fused MSE ----------
__global__ __launch_bounds__(256) void gather_kernel(const float* __restrict__ z_e,
                                                     const float* __restrict__ embed,
                                                     const int* __restrict__ codes,
                                                     float* __restrict__ out,
                                                     float* __restrict__ loss_sum) {
    __shared__ float zq[32][257];   // +1 pad: phase-2 reads stride 257 -> conflict-free
    __shared__ int cds[32];
    const int tid = threadIdx.x;
    const int n0 = blockIdx.x * 32;           // 32 tokens, single b (32 | 1024)
    if (tid < 32) cds[tid] = codes[n0 + tid];
    __syncthreads();
    #pragma unroll 4
    for (int it = 0; it < 32; ++it)           // coalesced 1KB row loads
        zq[it][tid] = embed[cds[it] * D_DIM + tid];
    __syncthreads();

    const int bb = n0 >> 10, hw0 = n0 & 1023;
    const int n32 = tid & 31, dl = tid >> 5;  // dl in 0..7
    float sq = 0.f;
    #pragma unroll 4
    for (int it = 0; it < 32; ++it) {
        int d = it * 8 + dl;
        float v = zq[n32][d];
        int pos = (bb * 256 + d) * 1024 + hw0 + n32;   // 128B-contiguous per 32 lanes
        out[pos] = v;
        out[4194304 + pos] = v;
        float df = v - z_e[pos];
        sq = fmaf(df, df, sq);
    }
    #pragma unroll
    for (int m = 1; m < 64; m <<= 1) sq += __shfl_xor(sq, m, 64);
    __shared__ float wsum[4];
    if ((tid & 63) == 0) wsum[tid >> 6] = sq;
    __syncthreads();
    if (tid == 0) atomicAdd(loss_sum, wsum[0] + wsum[1] + wsum[2] + wsum[3]);
}

__global__ __launch_bounds__(256) void stats_kernel(const int* __restrict__ counts,
                                                    const float* __restrict__ loss_sum,
                                                    float* __restrict__ out) {
    __shared__ double Hs[256];
    __shared__ int us[256];
    double H = 0.0; int used = 0;
    for (int k = threadIdx.x; k < K_CODES; k += 256) {
        int cnt = counts[k];
        if (cnt > 0) { double p = (double)cnt / 16384.0; H -= p * log(p); ++used; }
    }
    Hs[threadIdx.x] = H; us[threadIdx.x] = used;
    __syncthreads();
    for (int s = 128; s > 0; s >>= 1) {
        if (threadIdx.x < s) { Hs[threadIdx.x] += Hs[threadIdx.x + s]; us[threadIdx.x] += us[threadIdx.x + s]; }
        __syncthreads();
    }
    if (threadIdx.x == 0) {
        float loss = loss_sum[0] / 4194304.0f;
        float usedf = (float)us[0];
        out[8404992 + 0] = loss;
        out[8404992 + 1] = loss;
        out[8404992 + 2] = (float)exp(Hs[0]);
        out[8404992 + 3] = usedf;
        out[8404992 + 4] = usedf / 8192.0f;
        out[8404992 + 5] = 1.0f - usedf / 8192.0f;
    }
}

extern "C" void kernel_launch(void* const* d_in, const int* in_sizes, int n_in,
                              void* d_out, int out_size, void* d_ws, size_t ws_size,
                              hipStream_t stream) {
    const float* z_e   = (const float*)d_in[0];
    const float* embed = (const float*)d_in[1];
    float* out = (float*)d_out;
    float* ws  = (float*)d_ws;

    float*    e_norm   = ws;                         // [0, 8192)
    float*    z_norm   = ws + 8192;                  // [8192, 24576)
    int*      codes    = (int*)(ws + 24576);         // [24576, 40960)
    int*      counts   = (int*)(ws + 40960);         // [40960, 49152)
    float*    loss_sum = ws + 49152;                 // [49152] (zeroed via counts[8192])
    unsigned* ccount   = (unsigned*)(ws + 49408);    // [49408, 65792)
    unsigned* cand     = (unsigned*)(ws + 65792);    // 16384*112*4B -> [65792, 1900800)
    ushort*   e_bf     = (ushort*)(ws + 1900800);    // 8192*256*2B -> [1900800, 2949376)

    prep_kernel<<<2624, 256, 0, stream>>>(z_e, embed, e_norm, z_norm, e_bf, ccount, counts);
    mfma_argmin_kernel<<<1024, 512, 0, stream>>>(z_e, e_bf, e_norm, ccount, cand);
    rescore_kernel<<<4096, 256, 0, stream>>>(z_e, embed, e_norm, z_norm, ccount, cand, codes, out, counts);
    gather_kernel<<<512, 256, 0, stream>>>(z_e, embed, codes, out, loss_sum);
    stats_kernel<<<1, 256, 0, stream>>>(counts, loss_sum, out);
}

// Round 13
// 371.970 us; speedup vs baseline: 3.7077x; 3.7077x over previous
//
#include <hip/hip_runtime.h>

typedef __attribute__((ext_vector_type(8))) short bf16x8;
typedef __attribute__((ext_vector_type(4))) float f32x4;

#define D_DIM 256
#define K_CODES 8192
#define N_TOK 16384
#define MARGIN 2.5e-4f
#define CAP 96
#define LCAP 24
#define FILT_Q 200u
#define QSCALE 1638400.0f
#define QOFF 0.02f

// ---------- numpy-exact helpers (pairwise sum of squares, n=256) ----------
__device__ __forceinline__ float pw128_sq(const float* a, int stride) {
    float r[8];
    #pragma unroll
    for (int j = 0; j < 8; ++j) { float v = a[j * stride]; r[j] = __fmul_rn(v, v); }
    for (int i = 8; i < 128; i += 8) {
        #pragma unroll
        for (int j = 0; j < 8; ++j) { float v = a[(i + j) * stride]; r[j] = __fadd_rn(r[j], __fmul_rn(v, v)); }
    }
    return __fadd_rn(__fadd_rn(__fadd_rn(r[0], r[1]), __fadd_rn(r[2], r[3])),
                     __fadd_rn(__fadd_rn(r[4], r[5]), __fadd_rn(r[6], r[7])));
}
__device__ __forceinline__ float sumsq256(const float* a, int stride) {
    return __fadd_rn(pw128_sq(a, stride), pw128_sq(a + 128 * stride, stride));
}

__device__ __forceinline__ unsigned f2bf_u(float f) {   // RNE float->bf16 bits
    unsigned u = __float_as_uint(f);
    return (u + 0x7FFFu + ((u >> 16) & 1u)) >> 16;
}

// ---------- fused prep: ecvt (2048 blocks) + enorm16 (512) + znorm/zeroing (64) ----------
__global__ __launch_bounds__(256) void prep_kernel(const float* __restrict__ z_e,
                                                   const float* __restrict__ embed,
                                                   float* __restrict__ e_norm,
                                                   float* __restrict__ z_norm,
                                                   ushort* __restrict__ e_bf,
                                                   unsigned* __restrict__ ccount,
                                                   int* __restrict__ counts) {
    int bid = blockIdx.x;
    if (bid < 2048) {                      // ecvt: fp32 -> bf16 codebook
        int i = bid * 256 + threadIdx.x;   // 524288 float4s
        float4 v = reinterpret_cast<const float4*>(embed)[i];
        ushort4 o;
        o.x = (ushort)f2bf_u(v.x); o.y = (ushort)f2bf_u(v.y);
        o.z = (ushort)f2bf_u(v.z); o.w = (ushort)f2bf_u(v.w);
        reinterpret_cast<ushort4*>(e_bf)[i] = o;
    } else if (bid < 2560) {               // enorm: 16 lanes per code, numpy-pairwise-exact
        int tid = threadIdx.x;
        int code = (bid - 2048) * 16 + (tid >> 4);
        int sub = tid & 15;                // half = sub>>3, j = sub&7
        const float* base = embed + code * 256 + (sub >> 3) * 128 + (sub & 7);
        float v = base[0];
        float r = __fmul_rn(v, v);         // r[j] chain, i = 8..120 step 8
        #pragma unroll
        for (int i = 8; i < 128; i += 8) { v = base[i]; r = __fadd_rn(r, __fmul_rn(v, v)); }
        r = __fadd_rn(r, __shfl_xor(r, 1, 64));   // (r0+r1), (r2+r3), ...
        r = __fadd_rn(r, __shfl_xor(r, 2, 64));   // (r01+r23), (r45+r67)
        r = __fadd_rn(r, __shfl_xor(r, 4, 64));   // pw128
        r = __fadd_rn(r, __shfl_xor(r, 8, 64));   // pw128_lo + pw128_hi
        if (sub == 0) e_norm[code] = r;
    } else {                               // znorm + zero ccount/counts/loss_sum
        int n = (bid - 2560) * 256 + threadIdx.x;   // 16384
        int b = n >> 10, hw = n & 1023;
        z_norm[n] = sumsq256(z_e + b * 262144 + hw, 1024);
        ccount[n] = 0;
        if (n < 8193) counts[n] = 0;       // counts[8192] == adjacent loss_sum
    }
}

// ---------- MFMA approx scores: 3-buffer lookahead-2, LDS-local capture ----------
// grid 1024 = 256 token-panels x 4 slabs; slab constant per XCD; 4 blocks/CU.
// candidate word: (quantized_score:16 | code:16). Capture -> LDS; one flush at end.
// 4 blocks x LCAP(24) = 96 = CAP: global cand can never truncate.
__global__ __launch_bounds__(256, 4) void mfma_argmin_kernel(
    const float* __restrict__ z_e, const ushort* __restrict__ e_bf,
    const float* __restrict__ e_norm,
    unsigned* __restrict__ ccount, unsigned* __restrict__ cand)
{
    __shared__ char zs[32768];    // 64 token-rows x 512B bf16, byte ^= ((row&7)<<4)
    __shared__ unsigned cand_l[64][LCAP];
    __shared__ unsigned cnt_l[64];

    const int tid = threadIdx.x;
    const int l   = tid & 63;
    const int wv  = tid >> 6;
    const int col = l & 15;
    const int kg  = l >> 4;
    const int bid = (int)blockIdx.x;
    const int slab= (bid >> 1) & 3;              // == (XCD id)>>1: slab L2-resident per XCD
    const int mb  = ((bid >> 3) << 1) | (bid & 1);  // 0..255
    const int n0  = mb * 64;
    const int bb  = n0 >> 10;
    const int hw0 = n0 & 1023;
    const int cs  = slab * 2048 + wv * 512;      // this wave's 512-code range

    if (tid < 64) { cnt_l[tid] = 0; cand_l[tid][LCAP - 1] = 0xFFFFFFFFu; }

    // stage z panel: fp32 -> bf16, transpose [d][hw] -> [token][d], swizzled (round-3 proven)
    {
        const float* zb = z_e + bb * 262144 + hw0 + l;
        int swz = (l & 7) << 4;
        #pragma unroll 4
        for (int it = 0; it < 32; ++it) {
            int d = it * 8 + wv * 2;
            float a0 = zb[d * 1024];
            float a1 = zb[d * 1024 + 1024];
            unsigned pk = f2bf_u(a0) | (f2bf_u(a1) << 16);
            *(unsigned*)(zs + l * 512 + ((d * 2) ^ swz)) = pk;
        }
    }
    __syncthreads();

    const int a_swz = (col & 7) << 4;
    const char* bbase = (const char*)e_bf + (size_t)(cs + col) * 512 + kg * 16;
    const float* enb = e_norm + cs + col;

    float runmin[4][4];
    #pragma unroll
    for (int i0 = 0; i0 < 4; ++i0)
        #pragma unroll
        for (int i1 = 0; i1 < 4; ++i1) runmin[i0][i1] = 3.4e38f;

    f32x4 acc[4][4];
    bf16x8 b0[4], b1[4], b2[4];

    // step = t*8 + kb; t in [0,8) tiles of 64 codes, kb in [0,8) K-chunks of 32
    #define LDB(dst, step) { int _t = (step) >> 3, _kb = (step) & 7;                         \
        _Pragma("unroll")                                                                    \
        for (int nt = 0; nt < 4; ++nt)                                                       \
            dst[nt] = *(const bf16x8*)(bbase + _t * 32768 + nt * 8192 + _kb * 64); }

    #define COMPUTE(bf, step) {                                                              \
        int _kb = (step) & 7;                                                                \
        if (_kb == 0) {                                                                      \
            _Pragma("unroll")                                                                \
            for (int rt = 0; rt < 4; ++rt)                                                   \
                _Pragma("unroll")                                                            \
                for (int nt = 0; nt < 4; ++nt) acc[rt][nt] = f32x4{0.f, 0.f, 0.f, 0.f};      \
        }                                                                                    \
        int a_off = (_kb * 64 + kg * 16) ^ a_swz;                                            \
        _Pragma("unroll")                                                                    \
        for (int rt = 0; rt < 4; ++rt) {                                                     \
            bf16x8 afr = *(const bf16x8*)(zs + (rt * 16 + col) * 512 + a_off);               \
            _Pragma("unroll")                                                                \
            for (int nt = 0; nt < 4; ++nt)                                                   \
                acc[rt][nt] = __builtin_amdgcn_mfma_f32_16x16x32_bf16(afr, bf[nt], acc[rt][nt], 0, 0, 0); \
        }                                                                                    \
        if (_kb == 7) {                                                                      \
            int _t = (step) >> 3;                                                            \
            int cb = cs + _t * 64;                                                           \
            float en[4];                                                                     \
            _Pragma("unroll")                                                                \
            for (int nt = 0; nt < 4; ++nt) en[nt] = enb[_t * 64 + nt * 16];                  \
            _Pragma("unroll")                                                                \
            for (int rt = 0; rt < 4; ++rt)                                                   \
                _Pragma("unroll")                                                            \
                for (int nt = 0; nt < 4; ++nt)                                               \
                    _Pragma("unroll")                                                        \
                    for (int r = 0; r < 4; ++r)                                              \
                        acc[rt][nt][r] = fmaf(-2.0f, acc[rt][nt][r], en[nt]);                \
            _Pragma("unroll")                                                                \
            for (int rt = 0; rt < 4; ++rt) {                                                 \
                _Pragma("unroll")                                                            \
                for (int r = 0; r < 4; ++r) {                                                \
                    float m4 = fminf(fminf(acc[rt][0][r], acc[rt][1][r]),                    \
                                     fminf(acc[rt][2][r], acc[rt][3][r]));                   \
                    float tm = m4;                                                           \
                    tm = fminf(tm, __shfl_xor(tm, 1, 64));                                   \
                    tm = fminf(tm, __shfl_xor(tm, 2, 64));                                   \
                    tm = fminf(tm, __shfl_xor(tm, 4, 64));                                   \
                    tm = fminf(tm, __shfl_xor(tm, 8, 64));                                   \
                    float rm = fminf(runmin[rt][r], tm);                                     \
                    runmin[rt][r] = rm;                                                      \
                    float thr = rm + MARGIN;                                                 \
                    if (m4 < thr) {                                                          \
                        int tl = rt * 16 + kg * 4 + r;       /* block-local token */         \
                        _Pragma("unroll")                                                    \
                        for (int nt2 = 0; nt2 < 4; ++nt2) {                                  \
                            float s = acc[rt][nt2][r];                                       \
                            if (s < thr) {                                                   \
                                int q = (int)((s + QOFF) * QSCALE);                          \
                                q = q < 0 ? 0 : (q > 65535 ? 65535 : q);                     \
                                unsigned w = ((unsigned)q << 16)                             \
                                           | (unsigned)(cb + nt2 * 16 + col);                \
                                unsigned p = atomicAdd(&cnt_l[tl], 1u);     /* LDS atomic */ \
                                if (p < LCAP - 1) cand_l[tl][p] = w;                         \
                                else atomicMin(&cand_l[tl][LCAP - 1], w);                    \
                            }                                                                \
                        }                                                                    \
                    }                                                                        \
                }                                                                            \
            }                                                                                \
        }                                                                                    \
    }

    // 3-buffer rotation: issue-to-use distance = 2 COMPUTEs (~L2 latency).
    LDB(b0, 0); LDB(b1, 1);
    for (int sp = 0; sp < 21; ++sp) {       // steps 0..62 in 21 iterations of 3
        int s = sp * 3;
        LDB(b2, s + 2);        COMPUTE(b0, s);
        LDB(b0, (s + 3) & 63); COMPUTE(b1, s + 1);
        LDB(b1, (s + 4) & 63); COMPUTE(b2, s + 2);
    }
    COMPUTE(b0, 63);                        // tail (loaded at sp=20)
    #undef LDB
    #undef COMPUTE

    // flush block-local candidates: one global atomic per token per block
    __syncthreads();
    if (tid < 64) {
        unsigned cl = cnt_l[tid]; if (cl > LCAP) cl = LCAP;
        if (cl) {
            int token = n0 + tid;
            unsigned p = atomicAdd(&ccount[token], cl);
            for (unsigned i = 0; i < cl && p + i < CAP; ++i)
                cand[token * CAP + p + i] = cand_l[tid][i];
        }
    }
}

// ---------- filter by quantized approx score, exact fp32 rescore of survivors ----------
__global__ __launch_bounds__(256) void rescore_kernel(
    const float* __restrict__ z_e, const float* __restrict__ embed,
    const float* __restrict__ e_norm, const float* __restrict__ z_norm,
    const unsigned* __restrict__ ccount, const unsigned* __restrict__ cand,
    int* __restrict__ codes, float* __restrict__ out, int* __restrict__ counts)
{
    __shared__ float zrow[4][256];
    int wv = threadIdx.x >> 6, l = threadIdx.x & 63;
    int n = blockIdx.x * 4 + wv;
    // coalesced stage: thread d loads float4 = 4 consecutive tokens at depth d
    {
        int n0 = blockIdx.x * 4;
        int b = n0 >> 10, hw0 = n0 & 1023;
        float4 v = *reinterpret_cast<const float4*>(z_e + b * 262144 + threadIdx.x * 1024 + hw0);
        zrow[0][threadIdx.x] = v.x; zrow[1][threadIdx.x] = v.y;
        zrow[2][threadIdx.x] = v.z; zrow[3][threadIdx.x] = v.w;
    }
    __syncthreads();

    unsigned cnt = ccount[n]; if (cnt > CAP) cnt = CAP;
    unsigned c0 = ((unsigned)l      < cnt) ? cand[n * CAP + l]      : 0xFFFFFFFFu;
    unsigned c1 = ((unsigned)l + 64 < cnt) ? cand[n * CAP + l + 64] : 0xFFFFFFFFu;
    unsigned qm = min(c0 >> 16, c1 >> 16);
    #pragma unroll
    for (int m = 1; m < 64; m <<= 1) qm = min(qm, (unsigned)__shfl_xor((int)qm, m, 64));
    unsigned qthr = qm + FILT_Q;

    float best = 3.4e38f; int bidx = 0x7FFFFFFF;
    float zn = z_norm[n];
    #pragma unroll
    for (int pass = 0; pass < 2; ++pass) {
        unsigned cd = pass ? c1 : c0;
        if ((cd >> 16) <= qthr) {          // ~1-2 survivors per token
            int idx = (int)(cd & 0xFFFFu);
            const float* er = embed + idx * D_DIM;
            float dot = 0.f;
            for (int d = 0; d < 256; d += 4) {  // ascending-d fmaf chain (bit-identical to round-2)
                float4 e4 = *reinterpret_cast<const float4*>(er + d);
                dot = fmaf(zrow[wv][d],     e4.x, dot);
                dot = fmaf(zrow[wv][d + 1], e4.y, dot);
                dot = fmaf(zrow[wv][d + 2], e4.z, dot);
                dot = fmaf(zrow[wv][d + 3], e4.w, dot);
            }
            float s = __fsub_rn(__fadd_rn(zn, e_norm[idx]), __fmul_rn(2.0f, dot));
            if (s < best || (s == best && idx < bidx)) { best = s; bidx = idx; }
        }
    }
    #pragma unroll
    for (int m = 1; m < 64; m <<= 1) {      // min with lowest-index tie-break
        float s2 = __shfl_xor(best, m, 64);
        int   i2 = __shfl_xor(bidx, m, 64);
        if (s2 < best || (s2 == best && i2 < bidx)) { best = s2; bidx = i2; }
    }
    if (l == 0) {
        codes[n] = bidx;
        out[8388608 + n] = (float)bidx;
        atomicAdd(&counts[bidx], 1);
    }
}

// ---------- outputs: LDS-staged gather (coalesced embed reads) + fused MSE ----------
__global__ __launch_bounds__(256) void gather_kernel(const float* __restrict__ z_e,
                                                     const float* __restrict__ embed,
                                                     const int* __restrict__ codes,
                                                     float* __restrict__ out,
                                                     float* __restrict__ loss_sum) {
    __shared__ float zq[32][257];   // +1 pad: phase-2 reads stride 257 -> conflict-free
    __shared__ int cds[32];
    const int tid = threadIdx.x;
    const int n0 = blockIdx.x * 32;           // 32 tokens, single b (32 | 1024)
    if (tid < 32) cds[tid] = codes[n0 + tid];
    __syncthreads();
    #pragma unroll 4
    for (int it = 0; it < 32; ++it)           // coalesced 1KB row loads
        zq[it][tid] = embed[cds[it] * D_DIM + tid];
    __syncthreads();

    const int bb = n0 >> 10, hw0 = n0 & 1023;
    const int n32 = tid & 31, dl = tid >> 5;  // dl in 0..7
    float sq = 0.f;
    #pragma unroll 4
    for (int it = 0; it < 32; ++it) {
        int d = it * 8 + dl;
        float v = zq[n32][d];
        int pos = (bb * 256 + d) * 1024 + hw0 + n32;   // 128B-contiguous per 32 lanes
        out[pos] = v;
        out[4194304 + pos] = v;
        float df = v - z_e[pos];
        sq = fmaf(df, df, sq);
    }
    #pragma unroll
    for (int m = 1; m < 64; m <<= 1) sq += __shfl_xor(sq, m, 64);
    __shared__ float wsum[4];
    if ((tid & 63) == 0) wsum[tid >> 6] = sq;
    __syncthreads();
    if (tid == 0) atomicAdd(loss_sum, wsum[0] + wsum[1] + wsum[2] + wsum[3]);
}

__global__ __launch_bounds__(256) void stats_kernel(const int* __restrict__ counts,
                                                    const float* __restrict__ loss_sum,
                                                    float* __restrict__ out) {
    __shared__ double Hs[256];
    __shared__ int us[256];
    double H = 0.0; int used = 0;
    for (int k = threadIdx.x; k < K_CODES; k += 256) {
        int cnt = counts[k];
        if (cnt > 0) { double p = (double)cnt / 16384.0; H -= p * log(p); ++used; }
    }
    Hs[threadIdx.x] = H; us[threadIdx.x] = used;
    __syncthreads();
    for (int s = 128; s > 0; s >>= 1) {
        if (threadIdx.x < s) { Hs[threadIdx.x] += Hs[threadIdx.x + s]; us[threadIdx.x] += us[threadIdx.x + s]; }
        __syncthreads();
    }
    if (threadIdx.x == 0) {
        float loss = loss_sum[0] / 4194304.0f;
        float usedf = (float)us[0];
        out[8404992 + 0] = loss;
        out[8404992 + 1] = loss;
        out[8404992 + 2] = (float)exp(Hs[0]);
        out[8404992 + 3] = usedf;
        out[8404992 + 4] = usedf / 8192.0f;
        out[8404992 + 5] = 1.0f - usedf / 8192.0f;
    }
}

extern "C" void kernel_launch(void* const* d_in, const int* in_sizes, int n_in,
                              void* d_out, int out_size, void* d_ws, size_t ws_size,
                              hipStream_t stream) {
    const float* z_e   = (const float*)d_in[0];
    const float* embed = (const float*)d_in[1];
    float* out = (float*)d_out;
    float* ws  = (float*)d_ws;

    float*    e_norm   = ws;                         // [0, 8192)
    float*    z_norm   = ws + 8192;                  // [8192, 24576)
    int*      codes    = (int*)(ws + 24576);         // [24576, 40960)
    int*      counts   = (int*)(ws + 40960);         // [40960, 49152)
    float*    loss_sum = ws + 49152;                 // [49152] (zeroed via counts[8192])
    unsigned* ccount   = (unsigned*)(ws + 49408);    // [49408, 65792)
    unsigned* cand     = (unsigned*)(ws + 65792);    // 16384*96*4B -> [65792, 1638656)
    ushort*   e_bf     = (ushort*)(ws + 1638656);    // 8192*256*2B -> [1638656, 2687232)

    prep_kernel<<<2624, 256, 0, stream>>>(z_e, embed, e_norm, z_norm, e_bf, ccount, counts);
    mfma_argmin_kernel<<<1024, 256, 0, stream>>>(z_e, e_bf, e_norm, ccount, cand);
    rescore_kernel<<<4096, 256, 0, stream>>>(z_e, embed, e_norm, z_norm, ccount, cand, codes, out, counts);
    gather_kernel<<<512, 256, 0, stream>>>(z_e, embed, codes, out, loss_sum);
    stats_kernel<<<1, 256, 0, stream>>>(counts, loss_sum, out);
}

// Round 14
// 231.351 us; speedup vs baseline: 5.9613x; 1.6078x over previous
//
#include <hip/hip_runtime.h>

typedef __attribute__((ext_vector_type(8))) short bf16x8;
typedef __attribute__((ext_vector_type(4))) float f32x4;

#define D_DIM 256
#define K_CODES 8192
#define N_TOK 16384
#define LCAP 28
#define CAP_G 112
#define MQ 2400u          // capture/filter window in q19 counts (1.8e-4), HW-validated in round 12
#define QSCALE19 13107200.0f
#define QOFF 0.02f

// ---------- numpy-exact helpers (pairwise sum of squares, n=256) ----------
__device__ __forceinline__ float pw128_sq(const float* a, int stride) {
    float r[8];
    #pragma unroll
    for (int j = 0; j < 8; ++j) { float v = a[j * stride]; r[j] = __fmul_rn(v, v); }
    for (int i = 8; i < 128; i += 8) {
        #pragma unroll
        for (int j = 0; j < 8; ++j) { float v = a[(i + j) * stride]; r[j] = __fadd_rn(r[j], __fmul_rn(v, v)); }
    }
    return __fadd_rn(__fadd_rn(__fadd_rn(r[0], r[1]), __fadd_rn(r[2], r[3])),
                     __fadd_rn(__fadd_rn(r[4], r[5]), __fadd_rn(r[6], r[7])));
}
__device__ __forceinline__ float sumsq256(const float* a, int stride) {
    return __fadd_rn(pw128_sq(a, stride), pw128_sq(a + 128 * stride, stride));
}

__device__ __forceinline__ unsigned f2bf_u(float f) {   // RNE float->bf16 bits
    unsigned u = __float_as_uint(f);
    return (u + 0x7FFFu + ((u >> 16) & 1u)) >> 16;
}

__device__ __forceinline__ unsigned q19(float s) {      // monotone 19-bit score quantizer
    int q = (int)((s + QOFF) * QSCALE19);
    q = q < 0 ? 0 : (q > 524287 ? 524287 : q);
    return (unsigned)q;
}

// ---------- fused prep: ecvt (2048 blocks) + enorm16 (512) + znorm/zeroing (64) ----------
__global__ __launch_bounds__(256) void prep_kernel(const float* __restrict__ z_e,
                                                   const float* __restrict__ embed,
                                                   float* __restrict__ e_norm,
                                                   float* __restrict__ z_norm,
                                                   ushort* __restrict__ e_bf,
                                                   unsigned* __restrict__ ccount,
                                                   int* __restrict__ counts) {
    int bid = blockIdx.x;
    if (bid < 2048) {                      // ecvt: fp32 -> bf16 codebook
        int i = bid * 256 + threadIdx.x;   // 524288 float4s
        float4 v = reinterpret_cast<const float4*>(embed)[i];
        ushort4 o;
        o.x = (ushort)f2bf_u(v.x); o.y = (ushort)f2bf_u(v.y);
        o.z = (ushort)f2bf_u(v.z); o.w = (ushort)f2bf_u(v.w);
        reinterpret_cast<ushort4*>(e_bf)[i] = o;
    } else if (bid < 2560) {               // enorm: 16 lanes per code, numpy-pairwise-exact
        int tid = threadIdx.x;
        int code = (bid - 2048) * 16 + (tid >> 4);
        int sub = tid & 15;                // half = sub>>3, j = sub&7
        const float* base = embed + code * 256 + (sub >> 3) * 128 + (sub & 7);
        float v = base[0];
        float r = __fmul_rn(v, v);         // r[j] chain, i = 8..120 step 8
        #pragma unroll
        for (int i = 8; i < 128; i += 8) { v = base[i]; r = __fadd_rn(r, __fmul_rn(v, v)); }
        r = __fadd_rn(r, __shfl_xor(r, 1, 64));   // (r0+r1), (r2+r3), ...
        r = __fadd_rn(r, __shfl_xor(r, 2, 64));   // (r01+r23), (r45+r67)
        r = __fadd_rn(r, __shfl_xor(r, 4, 64));   // pw128
        r = __fadd_rn(r, __shfl_xor(r, 8, 64));   // pw128_lo + pw128_hi
        if (sub == 0) e_norm[code] = r;
    } else {                               // znorm + zero ccount/counts/loss_sum
        int n = (bid - 2560) * 256 + threadIdx.x;   // 16384
        int b = n >> 10, hw = n & 1023;
        z_norm[n] = sumsq256(z_e + b * 262144 + hw, 1024);
        ccount[n] = 0;
        if (n < 8193) counts[n] = 0;       // counts[8192] == adjacent loss_sum
    }
}

// ---------- MFMA approx scores: round-11 envelope + qmin_l capture (no per-tile shfl chains) ----------
// grid 1024 = 256 token-panels x 4 slabs; slab constant per XCD; 4 blocks/CU.
// candidate word: (q19:19 | code:13). Capture -> LDS; one flush at end.
// 4 blocks x LCAP(28) = 112 = CAP_G: global cand can never truncate.
__global__ __launch_bounds__(256, 4) void mfma_argmin_kernel(
    const float* __restrict__ z_e, const ushort* __restrict__ e_bf,
    const float* __restrict__ e_norm,
    unsigned* __restrict__ ccount, unsigned* __restrict__ cand)
{
    __shared__ char zs[32768];    // 64 token-rows x 512B bf16, byte ^= ((row&7)<<4)
    __shared__ unsigned cand_l[64][LCAP];
    __shared__ unsigned cnt_l[64];
    __shared__ unsigned qmin_l[64];   // block-shared running min (q19); stale reads safe (monotone)

    const int tid = threadIdx.x;
    const int l   = tid & 63;
    const int wv  = tid >> 6;
    const int col = l & 15;
    const int kg  = l >> 4;
    const int bid = (int)blockIdx.x;
    const int slab= (bid >> 1) & 3;              // == (XCD id)>>1: slab L2-resident per XCD
    const int mb  = ((bid >> 3) << 1) | (bid & 1);  // 0..255
    const int n0  = mb * 64;
    const int bb  = n0 >> 10;
    const int hw0 = n0 & 1023;
    const int cs  = slab * 2048 + wv * 512;      // this wave's 512-code range

    if (tid < 64) {
        cnt_l[tid] = 0;
        cand_l[tid][LCAP - 1] = 0xFFFFFFFFu;     // overflow atomicMin slot
        qmin_l[tid] = 0x0FFFFFFFu;               // large, no wrap with +MQ
    }

    // stage z panel: fp32 -> bf16, transpose [d][hw] -> [token][d], swizzled (round-3 proven)
    {
        const float* zb = z_e + bb * 262144 + hw0 + l;
        int swz = (l & 7) << 4;
        #pragma unroll 4
        for (int it = 0; it < 32; ++it) {
            int d = it * 8 + wv * 2;
            float a0 = zb[d * 1024];
            float a1 = zb[d * 1024 + 1024];
            unsigned pk = f2bf_u(a0) | (f2bf_u(a1) << 16);
            *(unsigned*)(zs + l * 512 + ((d * 2) ^ swz)) = pk;
        }
    }
    __syncthreads();

    const int a_swz = (col & 7) << 4;
    const char* bbase = (const char*)e_bf + (size_t)(cs + col) * 512 + kg * 16;
    const float* enb = e_norm + cs + col;

    f32x4 acc[4][4];
    bf16x8 bA[4], bB[4];

    // step = t*8 + kb; t in [0,8) tiles of 64 codes, kb in [0,8) K-chunks of 32
    #define LDB(dst, step) { int _t = (step) >> 3, _kb = (step) & 7;                         \
        _Pragma("unroll")                                                                    \
        for (int nt = 0; nt < 4; ++nt)                                                       \
            dst[nt] = *(const bf16x8*)(bbase + _t * 32768 + nt * 8192 + _kb * 64); }

    #define COMPUTE(bf, step) {                                                              \
        int _kb = (step) & 7;                                                                \
        if (_kb == 0) {                                                                      \
            _Pragma("unroll")                                                                \
            for (int rt = 0; rt < 4; ++rt)                                                   \
                _Pragma("unroll")                                                            \
                for (int nt = 0; nt < 4; ++nt) acc[rt][nt] = f32x4{0.f, 0.f, 0.f, 0.f};      \
        }                                                                                    \
        int a_off = (_kb * 64 + kg * 16) ^ a_swz;                                            \
        _Pragma("unroll")                                                                    \
        for (int rt = 0; rt < 4; ++rt) {                                                     \
            bf16x8 afr = *(const bf16x8*)(zs + (rt * 16 + col) * 512 + a_off);               \
            _Pragma("unroll")                                                                \
            for (int nt = 0; nt < 4; ++nt)                                                   \
                acc[rt][nt] = __builtin_amdgcn_mfma_f32_16x16x32_bf16(afr, bf[nt], acc[rt][nt], 0, 0, 0); \
        }                                                                                    \
        if (_kb == 7) {                                                                      \
            int _t = (step) >> 3;                                                            \
            int cb = cs + _t * 64;                                                           \
            float en[4];                                                                     \
            _Pragma("unroll")                                                                \
            for (int nt = 0; nt < 4; ++nt) en[nt] = enb[_t * 64 + nt * 16];                  \
            _Pragma("unroll")                                                                \
            for (int rt = 0; rt < 4; ++rt)                                                   \
                _Pragma("unroll")                                                            \
                for (int nt = 0; nt < 4; ++nt)                                               \
                    _Pragma("unroll")                                                        \
                    for (int r = 0; r < 4; ++r)                                              \
                        acc[rt][nt][r] = fmaf(-2.0f, acc[rt][nt][r], en[nt]);                \
            _Pragma("unroll")                                                                \
            for (int rt = 0; rt < 4; ++rt) {                                                 \
                _Pragma("unroll")                                                            \
                for (int r = 0; r < 4; ++r) {                                                \
                    float m4 = fminf(fminf(acc[rt][0][r], acc[rt][1][r]),                    \
                                     fminf(acc[rt][2][r], acc[rt][3][r]));                   \
                    int tl = rt * 16 + kg * 4 + r;       /* block-local token */             \
                    unsigned qtm;                                                            \
                    if (_t == 0) {          /* seed pass: exact 16-lane row min (4 shfls) */ \
                        float tm = m4;                                                       \
                        tm = fminf(tm, __shfl_xor(tm, 1, 64));                               \
                        tm = fminf(tm, __shfl_xor(tm, 2, 64));                               \
                        tm = fminf(tm, __shfl_xor(tm, 4, 64));                               \
                        tm = fminf(tm, __shfl_xor(tm, 8, 64));                               \
                        qtm = q19(tm);                                                       \
                    } else {                /* steady state: per-lane min, no DS chains */   \
                        qtm = q19(m4);                                                       \
                    }                                                                        \
                    unsigned cur = qmin_l[tl];           /* stale-read safe (monotone) */    \
                    unsigned thr = (cur < qtm ? cur : qtm) + MQ;                             \
                    if (q19(m4) < thr) {                                                     \
                        _Pragma("unroll")                                                    \
                        for (int nt2 = 0; nt2 < 4; ++nt2) {                                  \
                            unsigned qs = q19(acc[rt][nt2][r]);                              \
                            if (qs < thr) {                                                  \
                                unsigned w = (qs << 13)                                      \
                                           | (unsigned)(cb + nt2 * 16 + col);                \
                                unsigned p = atomicAdd(&cnt_l[tl], 1u);     /* LDS atomic */ \
                                if (p < LCAP - 1) cand_l[tl][p] = w;                         \
                                else atomicMin(&cand_l[tl][LCAP - 1], w);                    \
                            }                                                                \
                        }                                                                    \
                    }                                                                        \
                    if (qtm < cur) atomicMin(&qmin_l[tl], qtm);                              \
                }                                                                            \
            }                                                                                \
        }                                                                                    \
    }

    LDB(bA, 0);
    for (int sp = 0; sp < 32; ++sp) {       // 2 steps per iteration; buffers statically named
        int step = sp * 2;
        LDB(bB, step + 1);
        COMPUTE(bA, step);
        if (step + 2 < 64) LDB(bA, step + 2);
        COMPUTE(bB, step + 1);
    }
    #undef LDB
    #undef COMPUTE

    // flush block-local candidates: one global atomic per token per block
    __syncthreads();
    if (tid < 64) {
        unsigned cl = cnt_l[tid]; if (cl > LCAP) cl = LCAP;
        if (cl) {
            int token = n0 + tid;
            unsigned p = atomicAdd(&ccount[token], cl);
            for (unsigned i = 0; i < cl && p + i < CAP_G; ++i)
                cand[token * CAP_G + p + i] = cand_l[tid][i];
        }
    }
}

// ---------- filter by quantized approx score, exact fp32 rescore of survivors ----------
__global__ __launch_bounds__(256) void rescore_kernel(
    const float* __restrict__ z_e, const float* __restrict__ embed,
    const float* __restrict__ e_norm, const float* __restrict__ z_norm,
    const unsigned* __restrict__ ccount, const unsigned* __restrict__ cand,
    int* __restrict__ codes, float* __restrict__ out, int* __restrict__ counts)
{
    __shared__ float zrow[4][256];
    int wv = threadIdx.x >> 6, l = threadIdx.x & 63;
    int n = blockIdx.x * 4 + wv;
    // coalesced stage: thread d loads float4 = 4 consecutive tokens at depth d
    {
        int n0 = blockIdx.x * 4;
        int b = n0 >> 10, hw0 = n0 & 1023;
        float4 v = *reinterpret_cast<const float4*>(z_e + b * 262144 + threadIdx.x * 1024 + hw0);
        zrow[0][threadIdx.x] = v.x; zrow[1][threadIdx.x] = v.y;
        zrow[2][threadIdx.x] = v.z; zrow[3][threadIdx.x] = v.w;
    }
    __syncthreads();

    unsigned cnt = ccount[n]; if (cnt > CAP_G) cnt = CAP_G;
    unsigned c0 = ((unsigned)l      < cnt) ? cand[n * CAP_G + l]      : 0xFFFFFFFFu;
    unsigned c1 = ((unsigned)l + 64 < cnt) ? cand[n * CAP_G + l + 64] : 0xFFFFFFFFu;
    unsigned qm = min(c0 >> 13, c1 >> 13);
    #pragma unroll
    for (int m = 1; m < 64; m <<= 1) qm = min(qm, (unsigned)__shfl_xor((int)qm, m, 64));
    unsigned qthr = qm + MQ;

    float best = 3.4e38f; int bidx = 0x7FFFFFFF;
    float zn = z_norm[n];
    #pragma unroll
    for (int pass = 0; pass < 2; ++pass) {
        unsigned cd = pass ? c1 : c0;
        if ((cd >> 13) <= qthr) {          // ~1-2 survivors per token
            int idx = (int)(cd & 8191u);
            const float* er = embed + idx * D_DIM;
            float dot = 0.f;
            for (int d = 0; d < 256; d += 4) {  // ascending-d fmaf chain (bit-identical to round-2)
                float4 e4 = *reinterpret_cast<const float4*>(er + d);
                dot = fmaf(zrow[wv][d],     e4.x, dot);
                dot = fmaf(zrow[wv][d + 1], e4.y, dot);
                dot = fmaf(zrow[wv][d + 2], e4.z, dot);
                dot = fmaf(zrow[wv][d + 3], e4.w, dot);
            }
            float s = __fsub_rn(__fadd_rn(zn, e_norm[idx]), __fmul_rn(2.0f, dot));
            if (s < best || (s == best && idx < bidx)) { best = s; bidx = idx; }
        }
    }
    #pragma unroll
    for (int m = 1; m < 64; m <<= 1) {      // min with lowest-index tie-break
        float s2 = __shfl_xor(best, m, 64);
        int   i2 = __shfl_xor(bidx, m, 64);
        if (s2 < best || (s2 == best && i2 < bidx)) { best = s2; bidx = i2; }
    }
    if (l == 0) {
        codes[n] = bidx;
        out[8388608 + n] = (float)bidx;
        atomicAdd(&counts[bidx], 1);
    }
}

// ---------- outputs: LDS-staged gather (coalesced embed reads) + fused MSE ----------
__global__ __launch_bounds__(256) void gather_kernel(const float* __restrict__ z_e,
                                                     const float* __restrict__ embed,
                                                     const int* __restrict__ codes,
                                                     float* __restrict__ out,
                                                     float* __restrict__ loss_sum) {
    __shared__ float zq[32][257];   // +1 pad: phase-2 reads stride 257 -> conflict-free
    __shared__ int cds[32];
    const int tid = threadIdx.x;
    const int n0 = blockIdx.x * 32;           // 32 tokens, single b (32 | 1024)
    if (tid < 32) cds[tid] = codes[n0 + tid];
    __syncthreads();
    #pragma unroll 4
    for (int it = 0; it < 32; ++it)           // coalesced 1KB row loads
        zq[it][tid] = embed[cds[it] * D_DIM + tid];
    __syncthreads();

    const int bb = n0 >> 10, hw0 = n0 & 1023;
    const int n32 = tid & 31, dl = tid >> 5;  // dl in 0..7
    float sq = 0.f;
    #pragma unroll 4
    for (int it = 0; it < 32; ++it) {
        int d = it * 8 + dl;
        float v = zq[n32][d];
        int pos = (bb * 256 + d) * 1024 + hw0 + n32;   // 128B-contiguous per 32 lanes
        out[pos] = v;
        out[4194304 + pos] = v;
        float df = v - z_e[pos];
        sq = fmaf(df, df, sq);
    }
    #pragma unroll
    for (int m = 1; m < 64; m <<= 1) sq += __shfl_xor(sq, m, 64);
    __shared__ float wsum[4];
    if ((tid & 63) == 0) wsum[tid >> 6] = sq;
    __syncthreads();
    if (tid == 0) atomicAdd(loss_sum, wsum[0] + wsum[1] + wsum[2] + wsum[3]);
}

__global__ __launch_bounds__(256) void stats_kernel(const int* __restrict__ counts,
                                                    const float* __restrict__ loss_sum,
                                                    float* __restrict__ out) {
    __shared__ double Hs[256];
    __shared__ int us[256];
    double H = 0.0; int used = 0;
    for (int k = threadIdx.x; k < K_CODES; k += 256) {
        int cnt = counts[k];
        if (cnt > 0) { double p = (double)cnt / 16384.0; H -= p * log(p); ++used; }
    }
    Hs[threadIdx.x] = H; us[threadIdx.x] = used;
    __syncthreads();
    for (int s = 128; s > 0; s >>= 1) {
        if (threadIdx.x < s) { Hs[threadIdx.x] += Hs[threadIdx.x + s]; us[threadIdx.x] += us[threadIdx.x + s]; }
        __syncthreads();
    }
    if (threadIdx.x == 0) {
        float loss = loss_sum[0] / 4194304.0f;
        float usedf = (float)us[0];
        out[8404992 + 0] = loss;
        out[8404992 + 1] = loss;
        out[8404992 + 2] = (float)exp(Hs[0]);
        out[8404992 + 3] = usedf;
        out[8404992 + 4] = usedf / 8192.0f;
        out[8404992 + 5] = 1.0f - usedf / 8192.0f;
    }
}

extern "C" void kernel_launch(void* const* d_in, const int* in_sizes, int n_in,
                              void* d_out, int out_size, void* d_ws, size_t ws_size,
                              hipStream_t stream) {
    const float* z_e   = (const float*)d_in[0];
    const float* embed = (const float*)d_in[1];
    float* out = (float*)d_out;
    float* ws  = (float*)d_ws;

    float*    e_norm   = ws;                         // [0, 8192)
    float*    z_norm   = ws + 8192;                  // [8192, 24576)
    int*      codes    = (int*)(ws + 24576);         // [24576, 40960)
    int*      counts   = (int*)(ws + 40960);         // [40960, 49152)
    float*    loss_sum = ws + 49152;                 // [49152] (zeroed via counts[8192])
    unsigned* ccount   = (unsigned*)(ws + 49408);    // [49408, 65792)
    unsigned* cand     = (unsigned*)(ws + 65792);    // 16384*112*4B -> [65792, 1900800)
    ushort*   e_bf     = (ushort*)(ws + 1900800);    // 8192*256*2B -> [1900800, 2949376)

    prep_kernel<<<2624, 256, 0, stream>>>(z_e, embed, e_norm, z_norm, e_bf, ccount, counts);
    mfma_argmin_kernel<<<1024, 256, 0, stream>>>(z_e, e_bf, e_norm, ccount, cand);
    rescore_kernel<<<4096, 256, 0, stream>>>(z_e, embed, e_norm, z_norm, ccount, cand, codes, out, counts);
    gather_kernel<<<512, 256, 0, stream>>>(z_e, embed, codes, out, loss_sum);
    stats_kernel<<<1, 256, 0, stream>>>(counts, loss_sum, out);
}